// Round 11
// baseline (502.539 us; speedup 1.0000x reference)
//
#include <hip/hip_runtime.h>

#define N 4096
#define OUTW 12288   // n_x + n_e + n_i

// ---- Kernel A: compact spike indices per input row (ordered) + sx copy ----
__global__ void compact_spikes(const float* __restrict__ X, int* __restrict__ idx,
                               int* __restrict__ cnt, float* __restrict__ out, int T) {
    int t = blockIdx.x;
    const float* row = X + (size_t)t * N;
    __shared__ int counts[256];
    int tid = threadIdx.x;
    int base = tid * 16;
    float4 r0 = *(const float4*)(row + base);
    float4 r1 = *(const float4*)(row + base + 4);
    float4 r2 = *(const float4*)(row + base + 8);
    float4 r3 = *(const float4*)(row + base + 12);
    float* orow = out + (size_t)t * OUTW + base;   // fused sx copy
    *(float4*)(orow)      = r0;
    *(float4*)(orow + 4)  = r1;
    *(float4*)(orow + 8)  = r2;
    *(float4*)(orow + 12) = r3;
    float vals[16];
    *(float4*)(vals)      = r0;
    *(float4*)(vals + 4)  = r1;
    *(float4*)(vals + 8)  = r2;
    *(float4*)(vals + 12) = r3;
    int ks[16];
    int c = 0;
    #pragma unroll
    for (int q = 0; q < 16; ++q) {
        if (vals[q] != 0.0f) ks[c++] = base + q;
    }
    counts[tid] = c;
    __syncthreads();
    int off = 0;
    for (int i = 0; i < tid; ++i) off += counts[i];
    int* op = idx + (size_t)t * N;
    for (int q = 0; q < c; ++q) op[off + q] = ks[q];
    if (tid == 255) cnt[t] = off + c;
}

// ---- Fused time-sliced kernel -----------------------------------------------
// block 0: rec steps [ca, cb) -- all XW rows [ca, cb) were gathered by the
//          PREVIOUS kernel in the stream (no inter-block sync needed).
// blocks 1..(rb-ra): gather XW row r = ra + blockIdx.x - 1.
// LDS padded to ~98 KB/block => exactly ONE block per CU (2x98 > 160 KB):
// the rec block never shares issue slots with a gather block (round-10's
// 91-vs-64 us contention), and grid (<=101) <= 256 CUs so all blocks run
// concurrently on private CUs.
__global__ void __launch_bounds__(1024)
fused(const float* __restrict__ W, const int* __restrict__ idx,
      const int* __restrict__ cnt, float* __restrict__ XW,
      unsigned char* __restrict__ pk, float* __restrict__ state,
      int ra, int rb, int ca, int cb, int T) {
    __shared__ int sidx[4096];
    __shared__ unsigned int cS[3];
    __shared__ char lds_pad[80 * 1024];   // occupancy limiter: 1 block/CU
    const int tid = threadIdx.x;
    ((volatile char*)lds_pad)[tid] = 0;   // keep pad live (never read)

    if (blockIdx.x == 0) {
        if (ca >= cb) return;
        const int lane = tid & 63;
        float ve[4], ref[4];
        unsigned int R, E, zp;
        unsigned char pw;
        float* st = state + (size_t)tid * 12;
        if (ca == 0) {
            #pragma unroll
            for (int q = 0; q < 4; ++q) { ve[q] = -65.0f; ref[q] = 0.0f; }
            R = 0u; E = 0u; zp = 0u; pw = 0;
            if (tid == 0) { cS[0] = 0u; cS[1] = 0u; cS[2] = 0u; }
        } else {
            float4 a = *(float4*)(st);
            float4 b = *(float4*)(st + 4);
            uint4  c = *(uint4*)(st + 8);
            ve[0] = a.x; ve[1] = a.y; ve[2] = a.z; ve[3] = a.w;
            ref[0] = b.x; ref[1] = b.y; ref[2] = b.z; ref[3] = b.w;
            R = c.x; E = c.y; zp = c.z; pw = (unsigned char)c.w;
            if (tid == 0) {
                cS[0] = 0u; cS[1] = 0u;
                cS[2] = *(unsigned int*)(state + 12 * 1024);   // S(ca-1)
            }
        }
        const float4* xwp = (const float4*)XW + tid;   // row stride 1024 float4s
        float4 xw = xwp[(size_t)ca * 1024];
        unsigned char* pkp = pk + tid;
        int prev = 2, cur = 0, nxt = 1;
        __syncthreads();

        for (int t = ca; t < cb; ++t) {
            unsigned int Sint = cS[prev];             // S(t-1), broadcast read
            if (t > 0) pkp[(size_t)(t - 1) * 1024] = pw;   // deferred store
            float4 xw_n = xw;
            if (t + 1 < cb) xw_n = xwp[(size_t)(t + 1) * 1024];
            if (tid == 0) cS[nxt] = 0u;               // counter for step t+1
            // i-phase: SWAR over 4 byte-lanes (exact shortcut, round-2 proof)
            unsigned int nz = (R | (R >> 1)) & 0x01010101u;
            unsigned int z  = (nz ^ 0x01010101u) & E;
            R = (R - nz) | (z << 1);
            int c0 = __popcll(__ballot((z & 0x000000ffu) != 0u));
            int c1 = __popcll(__ballot((z & 0x0000ff00u) != 0u));
            int c2 = __popcll(__ballot((z & 0x00ff0000u) != 0u));
            int c3 = __popcll(__ballot((z & 0xff000000u) != 0u));
            if (lane == 0) atomicAdd(&cS[cur], (unsigned int)(c0 + c1 + c2 + c3));
            // e-phase: float exprs match verified rounds 3/5/9
            float Sf  = (float)Sint;
            float Sf1 = Sf - 1.0f;                    // exact integer
            const float xq[4] = {xw.x, xw.y, xw.z, xw.w};
            unsigned int sbits = 0u;
            #pragma unroll
            for (int q = 0; q < 4; ++q) {
                unsigned int bq = (zp >> (q * 8)) & 1u;     // s_i(t-1) bit
                float dS = bq ? Sf1 : Sf;       // == Sf - si_f[q], bit-exact
                float in_e = xq[q] - 17.5f * dS;            // exact product
                float in_sel = (ref[q] <= 0.0f) ? in_e : 0.0f;
                float v = ve[q] + 0.01f * (-65.0f - ve[q]) + in_sel;
                float rc = fmaxf(ref[q] - 1.0f, 0.0f);
                int s = (v >= -52.0f) ? 1 : 0;
                ref[q] = s ? 5.0f : rc;
                ve[q]  = s ? -65.0f : v;
                sbits |= (unsigned int)s << q;
            }
            E = (sbits * 0x00204081u) & 0x01010101u;     // bits0..3 -> bytes
            unsigned int znib = (z * 0x10204080u) >> 24; // bytes -> bits4..7
            pw = (unsigned char)(sbits | znib);
            zp = z;
            xw = xw_n;
            int tmp = prev; prev = cur; cur = nxt; nxt = tmp;
            __syncthreads();
        }
        // flush last word of this chunk (re-stored idempotently by next chunk)
        pkp[(size_t)(cb - 1) * 1024] = pw;
        if (cb < T) {   // save state for next chunk
            float4 a = {ve[0], ve[1], ve[2], ve[3]};
            float4 b = {ref[0], ref[1], ref[2], ref[3]};
            uint4  c = {R, E, zp, (unsigned int)pw};
            *(float4*)(st)     = a;
            *(float4*)(st + 4) = b;
            *(uint4*)(st + 8)  = c;
            if (tid == 0) *(unsigned int*)(state + 12 * 1024) = cS[prev];
        }
        return;
    }

    // ---------------- gather: one full XW row per block ----------------
    int r = ra + (int)blockIdx.x - 1;
    if (r >= rb) return;
    int col = tid * 4;
    float4 acc = {0.f, 0.f, 0.f, 0.f};
    if (r > 0) {
        int c = cnt[r - 1];
        const int* ip = idx + (size_t)(r - 1) * N;
        for (int s = tid; s < c; s += 1024) sidx[s] = ip[s];
        __syncthreads();
        int s = 0;
        for (; s + 4 <= c; s += 4) {                 // strict ascending order
            int k0 = sidx[s], k1 = sidx[s + 1], k2 = sidx[s + 2], k3 = sidx[s + 3];
            float4 w0 = *(const float4*)(W + (size_t)k0 * N + col);
            float4 w1 = *(const float4*)(W + (size_t)k1 * N + col);
            float4 w2 = *(const float4*)(W + (size_t)k2 * N + col);
            float4 w3 = *(const float4*)(W + (size_t)k3 * N + col);
            acc.x += w0.x; acc.y += w0.y; acc.z += w0.z; acc.w += w0.w;
            acc.x += w1.x; acc.y += w1.y; acc.z += w1.z; acc.w += w1.w;
            acc.x += w2.x; acc.y += w2.y; acc.z += w2.z; acc.w += w2.w;
            acc.x += w3.x; acc.y += w3.y; acc.z += w3.z; acc.w += w3.w;
        }
        for (; s < c; ++s) {
            int k = sidx[s];
            float4 w0 = *(const float4*)(W + (size_t)k * N + col);
            acc.x += w0.x; acc.y += w0.y; acc.z += w0.z; acc.w += w0.w;
        }
    }
    *(float4*)(XW + (size_t)r * N + col) = acc;
}

// ---- Kernel E: expand packed spike bits -> f32 output ----------------------
__global__ void expand(const unsigned char* __restrict__ pk, float* __restrict__ out, int T) {
    int i = blockIdx.x * 256 + threadIdx.x;   // [0, T*1024)
    if (i >= T * 1024) return;
    int t = i >> 10;
    int g = i & 1023;
    unsigned int b = pk[i];
    float* orow = out + (size_t)t * OUTW + N + (size_t)g * 4;
    float4 se4 = {(float)(b & 1u), (float)((b >> 1) & 1u),
                  (float)((b >> 2) & 1u), (float)((b >> 3) & 1u)};
    float4 si4 = {(float)((b >> 4) & 1u), (float)((b >> 5) & 1u),
                  (float)((b >> 6) & 1u), (float)((b >> 7) & 1u)};
    *(float4*)orow = se4;
    *(float4*)(orow + N) = si4;
}

extern "C" void kernel_launch(void* const* d_in, const int* in_sizes, int n_in,
                              void* d_out, int out_size, void* d_ws, size_t ws_size,
                              hipStream_t stream) {
    const float* X   = (const float*)d_in[0];   // [T, 4096]
    const float* Wxe = (const float*)d_in[1];   // [4096, 4096]
    int T = in_sizes[0] / N;
    float* out = (float*)d_out;

    // ws layout (footprint identical to proven rounds 1-10):
    //   XW  float[T*N] @ 0
    //   idx int[T*N]   @ T*N*4
    //     - pk overlays idx bytes [0, T*1024)            (<= idx row 32)
    //     - state overlays idx rows 40..43 (49156 B)     (read only by fused_0,
    //       which precedes the first state write at end of fused_1)
    //   cnt int[T]     @ 2*T*N*4
    float* XW = (float*)d_ws;
    int* idx  = (int*)((char*)d_ws + (size_t)T * N * 4);
    int* cnt  = (int*)((char*)d_ws + (size_t)2 * T * N * 4);
    unsigned char* pk = (unsigned char*)idx;
    float* state = (float*)((char*)idx + 40 * 16384);

    compact_spikes<<<T, 256, 0, stream>>>(X, idx, cnt, out, T);

    const int C = 100;                       // chunk size (5 chunks at T=500)
    int nch = (T + C - 1) / C;
    for (int i = 0; i <= nch; ++i) {
        int ra = i * C, rb = (i + 1) * C;    // gather rows for NEXT kernel
        if (ra > T) ra = T;
        if (rb > T) rb = T;
        int ca = (i - 1) * C, cb = i * C;    // rec steps (rows from PREV kernel)
        if (ca < 0) ca = 0;
        if (cb > T) cb = T;
        if (i == 0) { ca = cb = 0; }
        int grid = 1 + (rb - ra);
        fused<<<grid, 1024, 0, stream>>>(Wxe, idx, cnt, XW, pk, state,
                                         ra, rb, ca, cb, T);
    }

    expand<<<(T * 1024 + 255) / 256, 256, 0, stream>>>(pk, out, T);
}

// Round 12
// 487.670 us; speedup vs baseline: 1.0305x; 1.0305x over previous
//
#include <hip/hip_runtime.h>

#define N 4096
#define OUTW 12288   // n_x + n_e + n_i

// ---- Kernel A: compact spike indices per input row (ordered) + sx copy ----
__global__ void compact_spikes(const float* __restrict__ X, int* __restrict__ idx,
                               int* __restrict__ cnt, float* __restrict__ out, int T) {
    int t = blockIdx.x;
    const float* row = X + (size_t)t * N;
    __shared__ int counts[256];
    int tid = threadIdx.x;
    int base = tid * 16;
    float4 r0 = *(const float4*)(row + base);
    float4 r1 = *(const float4*)(row + base + 4);
    float4 r2 = *(const float4*)(row + base + 8);
    float4 r3 = *(const float4*)(row + base + 12);
    float* orow = out + (size_t)t * OUTW + base;   // fused sx copy
    *(float4*)(orow)      = r0;
    *(float4*)(orow + 4)  = r1;
    *(float4*)(orow + 8)  = r2;
    *(float4*)(orow + 12) = r3;
    float vals[16];
    *(float4*)(vals)      = r0;
    *(float4*)(vals + 4)  = r1;
    *(float4*)(vals + 8)  = r2;
    *(float4*)(vals + 12) = r3;
    int ks[16];
    int c = 0;
    #pragma unroll
    for (int q = 0; q < 16; ++q) {
        if (vals[q] != 0.0f) ks[c++] = base + q;
    }
    counts[tid] = c;
    __syncthreads();
    int off = 0;
    for (int i = 0; i < tid; ++i) off += counts[i];
    int* op = idx + (size_t)t * N;
    for (int q = 0; q < c; ++q) op[off + q] = ks[q];
    if (tid == 255) cnt[t] = off + c;
}

// ---- Fused time-sliced kernel -----------------------------------------------
// block 0: rec steps [ca, cb) (XW rows gathered by the PREVIOUS kernel in the
//          stream -- visibility by stream order, no inter-block sync).
// blocks 1..2*(rb-ra): gather; 2 blocks per XW row (half-row each, 2048 cols),
//          8-deep unrolled spike loop (8 independent row loads in flight;
//          adds strictly ascending-k => bit-identical sums).
__global__ void __launch_bounds__(1024)
fused(const float* __restrict__ W, const int* __restrict__ idx,
      const int* __restrict__ cnt, float* __restrict__ XW,
      unsigned char* __restrict__ pk, float* __restrict__ state,
      int ra, int rb, int ca, int cb, int T) {
    __shared__ int sidx[4096];
    __shared__ unsigned int cS[3];
    const int tid = threadIdx.x;

    if (blockIdx.x == 0) {
        if (ca >= cb) return;
        const int lane = tid & 63;
        float ve[4], ref[4];
        unsigned int R, E, zp;
        unsigned char pw;
        float* st = state + (size_t)tid * 12;
        if (ca == 0) {
            #pragma unroll
            for (int q = 0; q < 4; ++q) { ve[q] = -65.0f; ref[q] = 0.0f; }
            R = 0u; E = 0u; zp = 0u; pw = 0;
            if (tid == 0) { cS[0] = 0u; cS[1] = 0u; cS[2] = 0u; }
        } else {
            float4 a = *(float4*)(st);
            float4 b = *(float4*)(st + 4);
            uint4  c = *(uint4*)(st + 8);
            ve[0] = a.x; ve[1] = a.y; ve[2] = a.z; ve[3] = a.w;
            ref[0] = b.x; ref[1] = b.y; ref[2] = b.z; ref[3] = b.w;
            R = c.x; E = c.y; zp = c.z; pw = (unsigned char)c.w;
            if (tid == 0) {
                cS[0] = 0u; cS[1] = 0u;
                cS[2] = *(unsigned int*)(state + 12 * 1024);   // S(ca-1)
            }
        }
        const float4* xwp = (const float4*)XW + tid;   // row stride 1024 float4s
        float4 xw = xwp[(size_t)ca * 1024];
        unsigned char* pkp = pk + tid;
        int prev = 2, cur = 0, nxt = 1;
        __syncthreads();

        for (int t = ca; t < cb; ++t) {
            unsigned int Sint = cS[prev];             // S(t-1), broadcast read
            if (t > 0) pkp[(size_t)(t - 1) * 1024] = pw;   // deferred store
            float4 xw_n = xw;
            if (t + 1 < cb) xw_n = xwp[(size_t)(t + 1) * 1024];
            if (tid == 0) cS[nxt] = 0u;               // counter for step t+1
            // i-phase: SWAR over 4 byte-lanes (exact shortcut, round-2 proof)
            unsigned int nz = (R | (R >> 1)) & 0x01010101u;
            unsigned int z  = (nz ^ 0x01010101u) & E;
            R = (R - nz) | (z << 1);
            int c0 = __popcll(__ballot((z & 0x000000ffu) != 0u));
            int c1 = __popcll(__ballot((z & 0x0000ff00u) != 0u));
            int c2 = __popcll(__ballot((z & 0x00ff0000u) != 0u));
            int c3 = __popcll(__ballot((z & 0xff000000u) != 0u));
            if (lane == 0) atomicAdd(&cS[cur], (unsigned int)(c0 + c1 + c2 + c3));
            // e-phase: float exprs match verified rounds 3/5/9
            float Sf  = (float)Sint;
            float Sf1 = Sf - 1.0f;                    // exact integer
            const float xq[4] = {xw.x, xw.y, xw.z, xw.w};
            unsigned int sbits = 0u;
            #pragma unroll
            for (int q = 0; q < 4; ++q) {
                unsigned int bq = (zp >> (q * 8)) & 1u;     // s_i(t-1) bit
                float dS = bq ? Sf1 : Sf;       // == Sf - si_f[q], bit-exact
                float in_e = xq[q] - 17.5f * dS;            // exact product
                float in_sel = (ref[q] <= 0.0f) ? in_e : 0.0f;
                float v = ve[q] + 0.01f * (-65.0f - ve[q]) + in_sel;
                float rc = fmaxf(ref[q] - 1.0f, 0.0f);
                int s = (v >= -52.0f) ? 1 : 0;
                ref[q] = s ? 5.0f : rc;
                ve[q]  = s ? -65.0f : v;
                sbits |= (unsigned int)s << q;
            }
            E = (sbits * 0x00204081u) & 0x01010101u;     // bits0..3 -> bytes
            unsigned int znib = (z * 0x10204080u) >> 24; // bytes -> bits4..7
            pw = (unsigned char)(sbits | znib);
            zp = z;
            xw = xw_n;
            int tmp = prev; prev = cur; cur = nxt; nxt = tmp;
            __syncthreads();
        }
        // flush last word of this chunk (re-stored idempotently by next chunk)
        pkp[(size_t)(cb - 1) * 1024] = pw;
        if (cb < T) {   // save state for next chunk
            float4 a = {ve[0], ve[1], ve[2], ve[3]};
            float4 b = {ref[0], ref[1], ref[2], ref[3]};
            uint4  c = {R, E, zp, (unsigned int)pw};
            *(float4*)(st)     = a;
            *(float4*)(st + 4) = b;
            *(uint4*)(st + 8)  = c;
            if (tid == 0) *(unsigned int*)(state + 12 * 1024) = cS[prev];
        }
        return;
    }

    // -------- gather: half-row per block, 8-deep unrolled spike loop --------
    int b = (int)blockIdx.x - 1;
    int r = ra + (b >> 1);
    int half = b & 1;
    if (r >= rb) return;
    float4 acc = {0.f, 0.f, 0.f, 0.f};
    int col = (half << 11) + ((tid & 511) << 2);   // 2048 cols per half
    if (r > 0) {
        int c = cnt[r - 1];
        const int* ip = idx + (size_t)(r - 1) * N;
        for (int s = tid; s < c; s += 1024) sidx[s] = ip[s];
        __syncthreads();
        if (tid < 512) {
            const float* Wc = W + col;
            int s = 0;
            for (; s + 8 <= c; s += 8) {             // strict ascending order
                float4 w0 = *(const float4*)(Wc + (size_t)sidx[s]     * N);
                float4 w1 = *(const float4*)(Wc + (size_t)sidx[s + 1] * N);
                float4 w2 = *(const float4*)(Wc + (size_t)sidx[s + 2] * N);
                float4 w3 = *(const float4*)(Wc + (size_t)sidx[s + 3] * N);
                float4 w4 = *(const float4*)(Wc + (size_t)sidx[s + 4] * N);
                float4 w5 = *(const float4*)(Wc + (size_t)sidx[s + 5] * N);
                float4 w6 = *(const float4*)(Wc + (size_t)sidx[s + 6] * N);
                float4 w7 = *(const float4*)(Wc + (size_t)sidx[s + 7] * N);
                acc.x += w0.x; acc.y += w0.y; acc.z += w0.z; acc.w += w0.w;
                acc.x += w1.x; acc.y += w1.y; acc.z += w1.z; acc.w += w1.w;
                acc.x += w2.x; acc.y += w2.y; acc.z += w2.z; acc.w += w2.w;
                acc.x += w3.x; acc.y += w3.y; acc.z += w3.z; acc.w += w3.w;
                acc.x += w4.x; acc.y += w4.y; acc.z += w4.z; acc.w += w4.w;
                acc.x += w5.x; acc.y += w5.y; acc.z += w5.z; acc.w += w5.w;
                acc.x += w6.x; acc.y += w6.y; acc.z += w6.z; acc.w += w6.w;
                acc.x += w7.x; acc.y += w7.y; acc.z += w7.z; acc.w += w7.w;
            }
            for (; s < c; ++s) {
                float4 w0 = *(const float4*)(Wc + (size_t)sidx[s] * N);
                acc.x += w0.x; acc.y += w0.y; acc.z += w0.z; acc.w += w0.w;
            }
        }
    }
    if (tid < 512) *(float4*)(XW + (size_t)r * N + col) = acc;
}

// ---- Kernel E: expand packed spike bits -> f32 output ----------------------
__global__ void expand(const unsigned char* __restrict__ pk, float* __restrict__ out, int T) {
    int i = blockIdx.x * 256 + threadIdx.x;   // [0, T*1024)
    if (i >= T * 1024) return;
    int t = i >> 10;
    int g = i & 1023;
    unsigned int b = pk[i];
    float* orow = out + (size_t)t * OUTW + N + (size_t)g * 4;
    float4 se4 = {(float)(b & 1u), (float)((b >> 1) & 1u),
                  (float)((b >> 2) & 1u), (float)((b >> 3) & 1u)};
    float4 si4 = {(float)((b >> 4) & 1u), (float)((b >> 5) & 1u),
                  (float)((b >> 6) & 1u), (float)((b >> 7) & 1u)};
    *(float4*)orow = se4;
    *(float4*)(orow + N) = si4;
}

extern "C" void kernel_launch(void* const* d_in, const int* in_sizes, int n_in,
                              void* d_out, int out_size, void* d_ws, size_t ws_size,
                              hipStream_t stream) {
    const float* X   = (const float*)d_in[0];   // [T, 4096]
    const float* Wxe = (const float*)d_in[1];   // [4096, 4096]
    int T = in_sizes[0] / N;
    float* out = (float*)d_out;

    // ws layout (footprint identical to proven rounds 1-11):
    //   XW  float[T*N] @ 0
    //   idx int[T*N]   @ T*N*4
    //     - pk overlays idx bytes [0, T*1024)            (<= idx row 32)
    //     - state overlays idx rows 40..43               (read only by chunk i
    //       rec, written at end of chunk i; idx rows dead after their gather)
    //   cnt int[T]     @ 2*T*N*4
    float* XW = (float*)d_ws;
    int* idx  = (int*)((char*)d_ws + (size_t)T * N * 4);
    int* cnt  = (int*)((char*)d_ws + (size_t)2 * T * N * 4);
    unsigned char* pk = (unsigned char*)idx;
    float* state = (float*)((char*)idx + 40 * 16384);

    compact_spikes<<<T, 256, 0, stream>>>(X, idx, cnt, out, T);

    const int C = 100;                       // chunk size (5 chunks at T=500)
    int nch = (T + C - 1) / C;
    for (int i = 0; i <= nch; ++i) {
        int ra = i * C, rb = (i + 1) * C;    // gather rows for NEXT kernel
        if (ra > T) ra = T;
        if (rb > T) rb = T;
        int ca = (i - 1) * C, cb = i * C;    // rec steps (rows from PREV kernel)
        if (ca < 0) ca = 0;
        if (cb > T) cb = T;
        if (i == 0) { ca = cb = 0; }
        int grid = 1 + 2 * (rb - ra);
        fused<<<grid, 1024, 0, stream>>>(Wxe, idx, cnt, XW, pk, state,
                                         ra, rb, ca, cb, T);
    }

    expand<<<(T * 1024 + 255) / 256, 256, 0, stream>>>(pk, out, T);
}

// Round 13
// 463.409 us; speedup vs baseline: 1.0844x; 1.0524x over previous
//
#include <hip/hip_runtime.h>

#define N 4096
#define OUTW 12288   // n_x + n_e + n_i

// ---- Kernel A: compact spike indices per input row (ordered) + sx copy ----
__global__ void compact_spikes(const float* __restrict__ X, int* __restrict__ idx,
                               int* __restrict__ cnt, float* __restrict__ out, int T) {
    int t = blockIdx.x;
    const float* row = X + (size_t)t * N;
    __shared__ int counts[256];
    int tid = threadIdx.x;
    int base = tid * 16;
    float4 r0 = *(const float4*)(row + base);
    float4 r1 = *(const float4*)(row + base + 4);
    float4 r2 = *(const float4*)(row + base + 8);
    float4 r3 = *(const float4*)(row + base + 12);
    float* orow = out + (size_t)t * OUTW + base;   // fused sx copy
    *(float4*)(orow)      = r0;
    *(float4*)(orow + 4)  = r1;
    *(float4*)(orow + 8)  = r2;
    *(float4*)(orow + 12) = r3;
    float vals[16];
    *(float4*)(vals)      = r0;
    *(float4*)(vals + 4)  = r1;
    *(float4*)(vals + 8)  = r2;
    *(float4*)(vals + 12) = r3;
    int ks[16];
    int c = 0;
    #pragma unroll
    for (int q = 0; q < 16; ++q) {
        if (vals[q] != 0.0f) ks[c++] = base + q;
    }
    counts[tid] = c;
    __syncthreads();
    int off = 0;
    for (int i = 0; i < tid; ++i) off += counts[i];
    int* op = idx + (size_t)t * N;
    for (int q = 0; q < c; ++q) op[off + q] = ks[q];
    if (tid == 255) cnt[t] = off + c;
}

// ---- Fused time-sliced kernel -----------------------------------------------
// block 0: rec steps [ca, cb) (XW rows gathered by the PREVIOUS kernel in the
//          stream -- visibility by stream order, no inter-block sync).
// blocks b>=1: gather, XCD-pinned column slices. slice s = (b-1)&7 (blocks of
//          one slice land on one XCD under round-robin blockIdx->XCD), rows
//          [ra+8p, ra+8p+8) where p=(b-1)>>3. 1024 thr = 8 groups x 128; each
//          group owns one row x 512-col slice; ascending-k 8-deep float4 loop
//          (bit-identical sums to rounds 1-12).
__global__ void __launch_bounds__(1024)
fused(const float* __restrict__ W, const int* __restrict__ idx,
      const int* __restrict__ cnt, float* __restrict__ XW,
      unsigned char* __restrict__ pk, float* __restrict__ state,
      int ra, int rb, int ca, int cb, int T) {
    __shared__ unsigned int cS[3];
    const int tid = threadIdx.x;

    if (blockIdx.x == 0) {
        if (ca >= cb) return;
        const int lane = tid & 63;
        float ve[4], ref[4];
        unsigned int R, E, zp;
        unsigned char pw;
        float* st = state + (size_t)tid * 12;
        if (ca == 0) {
            #pragma unroll
            for (int q = 0; q < 4; ++q) { ve[q] = -65.0f; ref[q] = 0.0f; }
            R = 0u; E = 0u; zp = 0u; pw = 0;
            if (tid == 0) { cS[0] = 0u; cS[1] = 0u; cS[2] = 0u; }
        } else {
            float4 a = *(float4*)(st);
            float4 b = *(float4*)(st + 4);
            uint4  c = *(uint4*)(st + 8);
            ve[0] = a.x; ve[1] = a.y; ve[2] = a.z; ve[3] = a.w;
            ref[0] = b.x; ref[1] = b.y; ref[2] = b.z; ref[3] = b.w;
            R = c.x; E = c.y; zp = c.z; pw = (unsigned char)c.w;
            if (tid == 0) {
                cS[0] = 0u; cS[1] = 0u;
                cS[2] = *(unsigned int*)(state + 12 * 1024);   // S(ca-1)
            }
        }
        const float4* xwp = (const float4*)XW + tid;   // row stride 1024 float4s
        float4 xw = xwp[(size_t)ca * 1024];
        unsigned char* pkp = pk + tid;
        int prev = 2, cur = 0, nxt = 1;
        __syncthreads();

        for (int t = ca; t < cb; ++t) {
            unsigned int Sint = cS[prev];             // S(t-1), broadcast read
            if (t > 0) pkp[(size_t)(t - 1) * 1024] = pw;   // deferred store
            float4 xw_n = xw;
            if (t + 1 < cb) xw_n = xwp[(size_t)(t + 1) * 1024];
            if (tid == 0) cS[nxt] = 0u;               // counter for step t+1
            // i-phase: SWAR over 4 byte-lanes (exact shortcut, round-2 proof)
            unsigned int nz = (R | (R >> 1)) & 0x01010101u;
            unsigned int z  = (nz ^ 0x01010101u) & E;
            R = (R - nz) | (z << 1);
            int c0 = __popcll(__ballot((z & 0x000000ffu) != 0u));
            int c1 = __popcll(__ballot((z & 0x0000ff00u) != 0u));
            int c2 = __popcll(__ballot((z & 0x00ff0000u) != 0u));
            int c3 = __popcll(__ballot((z & 0xff000000u) != 0u));
            if (lane == 0) atomicAdd(&cS[cur], (unsigned int)(c0 + c1 + c2 + c3));
            // e-phase: float exprs match verified rounds 3/5/9
            float Sf  = (float)Sint;
            float Sf1 = Sf - 1.0f;                    // exact integer
            const float xq[4] = {xw.x, xw.y, xw.z, xw.w};
            unsigned int sbits = 0u;
            #pragma unroll
            for (int q = 0; q < 4; ++q) {
                unsigned int bq = (zp >> (q * 8)) & 1u;     // s_i(t-1) bit
                float dS = bq ? Sf1 : Sf;       // == Sf - si_f[q], bit-exact
                float in_e = xq[q] - 17.5f * dS;            // exact product
                float in_sel = (ref[q] <= 0.0f) ? in_e : 0.0f;
                float v = ve[q] + 0.01f * (-65.0f - ve[q]) + in_sel;
                float rc = fmaxf(ref[q] - 1.0f, 0.0f);
                int s = (v >= -52.0f) ? 1 : 0;
                ref[q] = s ? 5.0f : rc;
                ve[q]  = s ? -65.0f : v;
                sbits |= (unsigned int)s << q;
            }
            E = (sbits * 0x00204081u) & 0x01010101u;     // bits0..3 -> bytes
            unsigned int znib = (z * 0x10204080u) >> 24; // bytes -> bits4..7
            pw = (unsigned char)(sbits | znib);
            zp = z;
            xw = xw_n;
            int tmp = prev; prev = cur; cur = nxt; nxt = tmp;
            __syncthreads();
        }
        // flush last word of this chunk (re-stored idempotently by next chunk)
        pkp[(size_t)(cb - 1) * 1024] = pw;
        if (cb < T) {   // save state for next chunk
            float4 a = {ve[0], ve[1], ve[2], ve[3]};
            float4 b = {ref[0], ref[1], ref[2], ref[3]};
            uint4  c = {R, E, zp, (unsigned int)pw};
            *(float4*)(st)     = a;
            *(float4*)(st + 4) = b;
            *(uint4*)(st + 8)  = c;
            if (tid == 0) *(unsigned int*)(state + 12 * 1024) = cS[prev];
        }
        return;
    }

    // ---- gather: 8 rows x 512-col slice per block, XCD-pinned by slice ----
    __shared__ int sidx[8][512];
    int b = (int)blockIdx.x - 1;
    int s8 = b & 7;                       // slice (consistent XCD under %8 rr)
    int p  = b >> 3;
    int g  = tid >> 7;                    // group 0..7 -> row
    int ln = tid & 127;                   // lane within group
    int r  = ra + 8 * p + g;
    int valid = (r < rb);
    int c = 0;
    const int* ip = nullptr;
    if (valid && r > 0) {
        c = cnt[r - 1];
        ip = idx + (size_t)(r - 1) * N;
        int lim = c < 512 ? c : 512;
        for (int j = ln; j < lim; j += 128) sidx[g][j] = ip[j];
    }
    __syncthreads();
    if (!valid) return;
    int col = (s8 << 9) + (ln << 2);
    float4 acc = {0.f, 0.f, 0.f, 0.f};
    if (r > 0) {
        const float* Wc = W + col;
        const int* sg = sidx[g];
        int lim = c < 512 ? c : 512;
        int s = 0;
        for (; s + 8 <= lim; s += 8) {              // strict ascending order
            float4 w0 = *(const float4*)(Wc + (size_t)sg[s]     * N);
            float4 w1 = *(const float4*)(Wc + (size_t)sg[s + 1] * N);
            float4 w2 = *(const float4*)(Wc + (size_t)sg[s + 2] * N);
            float4 w3 = *(const float4*)(Wc + (size_t)sg[s + 3] * N);
            float4 w4 = *(const float4*)(Wc + (size_t)sg[s + 4] * N);
            float4 w5 = *(const float4*)(Wc + (size_t)sg[s + 5] * N);
            float4 w6 = *(const float4*)(Wc + (size_t)sg[s + 6] * N);
            float4 w7 = *(const float4*)(Wc + (size_t)sg[s + 7] * N);
            acc.x += w0.x; acc.y += w0.y; acc.z += w0.z; acc.w += w0.w;
            acc.x += w1.x; acc.y += w1.y; acc.z += w1.z; acc.w += w1.w;
            acc.x += w2.x; acc.y += w2.y; acc.z += w2.z; acc.w += w2.w;
            acc.x += w3.x; acc.y += w3.y; acc.z += w3.z; acc.w += w3.w;
            acc.x += w4.x; acc.y += w4.y; acc.z += w4.z; acc.w += w4.w;
            acc.x += w5.x; acc.y += w5.y; acc.z += w5.z; acc.w += w5.w;
            acc.x += w6.x; acc.y += w6.y; acc.z += w6.z; acc.w += w6.w;
            acc.x += w7.x; acc.y += w7.y; acc.z += w7.z; acc.w += w7.w;
        }
        for (; s < lim; ++s) {
            float4 w0 = *(const float4*)(Wc + (size_t)sg[s] * N);
            acc.x += w0.x; acc.y += w0.y; acc.z += w0.z; acc.w += w0.w;
        }
        for (; s < c; ++s) {                        // ultra-rare spill >512
            float4 w0 = *(const float4*)(Wc + (size_t)ip[s] * N);
            acc.x += w0.x; acc.y += w0.y; acc.z += w0.z; acc.w += w0.w;
        }
    }
    *(float4*)(XW + (size_t)r * N + col) = acc;
}

// ---- Kernel E: expand packed spike bits -> f32 output ----------------------
__global__ void expand(const unsigned char* __restrict__ pk, float* __restrict__ out, int T) {
    int i = blockIdx.x * 256 + threadIdx.x;   // [0, T*1024)
    if (i >= T * 1024) return;
    int t = i >> 10;
    int g = i & 1023;
    unsigned int b = pk[i];
    float* orow = out + (size_t)t * OUTW + N + (size_t)g * 4;
    float4 se4 = {(float)(b & 1u), (float)((b >> 1) & 1u),
                  (float)((b >> 2) & 1u), (float)((b >> 3) & 1u)};
    float4 si4 = {(float)((b >> 4) & 1u), (float)((b >> 5) & 1u),
                  (float)((b >> 6) & 1u), (float)((b >> 7) & 1u)};
    *(float4*)orow = se4;
    *(float4*)(orow + N) = si4;
}

extern "C" void kernel_launch(void* const* d_in, const int* in_sizes, int n_in,
                              void* d_out, int out_size, void* d_ws, size_t ws_size,
                              hipStream_t stream) {
    const float* X   = (const float*)d_in[0];   // [T, 4096]
    const float* Wxe = (const float*)d_in[1];   // [4096, 4096]
    int T = in_sizes[0] / N;
    float* out = (float*)d_out;

    // ws layout (footprint identical to proven rounds 1-12):
    //   XW  float[T*N] @ 0
    //   idx int[T*N]   @ T*N*4
    //     - pk overlays idx bytes [0, T*1024)
    //     - state overlays idx rows 40..43
    //   cnt int[T]     @ 2*T*N*4
    float* XW = (float*)d_ws;
    int* idx  = (int*)((char*)d_ws + (size_t)T * N * 4);
    int* cnt  = (int*)((char*)d_ws + (size_t)2 * T * N * 4);
    unsigned char* pk = (unsigned char*)idx;
    float* state = (float*)((char*)idx + 40 * 16384);

    compact_spikes<<<T, 256, 0, stream>>>(X, idx, cnt, out, T);

    // chunk bounds: 100-step chunks with an 80/20 tail split (cuts the final
    // rec-only kernel from 64us to ~13us)
    int bounds[16];
    int nb = 0;
    bounds[nb++] = 0;
    if (T >= 140) {
        for (int x = 100; x <= T - 140; x += 100) bounds[nb++] = x;
        bounds[nb++] = T - 20;
    }
    bounds[nb++] = T;
    int nch = nb - 1;

    for (int i = 0; i <= nch; ++i) {
        int ra = (i < nch) ? bounds[i] : T;       // gather rows for NEXT kernel
        int rb = (i < nch) ? bounds[i + 1] : T;
        int ca = (i >= 1) ? bounds[i - 1] : 0;    // rec steps (from PREV kernel)
        int cb = (i >= 1) ? bounds[i] : 0;
        int nrow = rb - ra;
        int grid = 1 + 8 * ((nrow + 7) / 8);
        fused<<<grid, 1024, 0, stream>>>(Wxe, idx, cnt, XW, pk, state,
                                         ra, rb, ca, cb, T);
    }

    expand<<<(T * 1024 + 255) / 256, 256, 0, stream>>>(pk, out, T);
}